// Round 5
// baseline (299.303 us; speedup 1.0000x reference)
//
#include <hip/hip_runtime.h>
#include <hip/hip_bf16.h>
#include <math.h>
#include <stdint.h>

#define N_ROWS 8192
#define DIM 512
#define INV_TAU 5.0f
#define EXP5 148.41315910257660342f   // exp(1/tau) = exp(5)
#define BM 128
#define BN 256

typedef float f32x4 __attribute__((ext_vector_type(4)));
typedef __bf16 bf16x8 __attribute__((ext_vector_type(8)));
typedef __bf16 bf16x4 __attribute__((ext_vector_type(4)));

__device__ __forceinline__ void gload_lds16(const void* g, void* l) {
  __builtin_amdgcn_global_load_lds(
      (__attribute__((address_space(1))) void*)(void*)g,
      (__attribute__((address_space(3))) void*)l,
      16, 0, 0);
}

// One WAVE per row (no barriers): L2 norms, fp32 diag dot, bf16 h1,h2.
// Also zeroes accumulator arrays and out. grid = 2048 blocks x 256.
__global__ __launch_bounds__(256) void normalize_kernel(
    const float* __restrict__ z1, const float* __restrict__ z2,
    __hip_bfloat16* __restrict__ h1, __hip_bfloat16* __restrict__ h2,
    float* __restrict__ dvec,
    float* __restrict__ r1, float* __restrict__ r2,
    float* __restrict__ brow, float* __restrict__ bcol,
    float* __restrict__ out) {
  const int t = threadIdx.x;
  const int lane = t & 63;
  const int row = blockIdx.x * 4 + (t >> 6);
  const float4* p1 = (const float4*)(z1 + (size_t)row * DIM);
  const float4* p2 = (const float4*)(z2 + (size_t)row * DIM);
  const float4 a0 = p1[lane], a1 = p1[lane + 64];
  const float4 b0 = p2[lane], b1 = p2[lane + 64];
  float s1 = a0.x*a0.x + a0.y*a0.y + a0.z*a0.z + a0.w*a0.w
           + a1.x*a1.x + a1.y*a1.y + a1.z*a1.z + a1.w*a1.w;
  float s2 = b0.x*b0.x + b0.y*b0.y + b0.z*b0.z + b0.w*b0.w
           + b1.x*b1.x + b1.y*b1.y + b1.z*b1.z + b1.w*b1.w;
  float s3 = a0.x*b0.x + a0.y*b0.y + a0.z*b0.z + a0.w*b0.w
           + a1.x*b1.x + a1.y*b1.y + a1.z*b1.z + a1.w*b1.w;
  for (int m = 32; m; m >>= 1) {
    s1 += __shfl_xor(s1, m);
    s2 += __shfl_xor(s2, m);
    s3 += __shfl_xor(s3, m);
  }
  const float inv1 = 1.0f / fmaxf(sqrtf(s1), 1e-12f);
  const float inv2 = 1.0f / fmaxf(sqrtf(s2), 1e-12f);
  union { bf16x4 v; __hip_bfloat16 e[4]; } u;
  __hip_bfloat16* o1 = h1 + (size_t)row * DIM;
  __hip_bfloat16* o2 = h2 + (size_t)row * DIM;
  u.e[0] = __float2bfloat16(a0.x*inv1); u.e[1] = __float2bfloat16(a0.y*inv1);
  u.e[2] = __float2bfloat16(a0.z*inv1); u.e[3] = __float2bfloat16(a0.w*inv1);
  *(bf16x4*)(o1 + lane*4) = u.v;
  u.e[0] = __float2bfloat16(a1.x*inv1); u.e[1] = __float2bfloat16(a1.y*inv1);
  u.e[2] = __float2bfloat16(a1.z*inv1); u.e[3] = __float2bfloat16(a1.w*inv1);
  *(bf16x4*)(o1 + 256 + lane*4) = u.v;
  u.e[0] = __float2bfloat16(b0.x*inv2); u.e[1] = __float2bfloat16(b0.y*inv2);
  u.e[2] = __float2bfloat16(b0.z*inv2); u.e[3] = __float2bfloat16(b0.w*inv2);
  *(bf16x4*)(o2 + lane*4) = u.v;
  u.e[0] = __float2bfloat16(b1.x*inv2); u.e[1] = __float2bfloat16(b1.y*inv2);
  u.e[2] = __float2bfloat16(b1.z*inv2); u.e[3] = __float2bfloat16(b1.w*inv2);
  *(bf16x4*)(o2 + 256 + lane*4) = u.v;
  if (lane == 0) {
    dvec[row] = s3 * inv1 * inv2;
    r1[row] = 0.0f; r2[row] = 0.0f; brow[row] = 0.0f; bcol[row] = 0.0f;
    if (row == 0) out[0] = 0.0f;
  }
}

// grid (64, 32, 3); tile 128x256; 4 waves 2x2, 4x8 frags 16x16x32 bf16 MFMA.
// Single-barrier double-buffered K-loop: stage(k+1) issued AFTER the barrier
// of iter k, so the compiler's vmcnt(0)-before-s_barrier drains loads that
// overlapped a full compute phase. LDS 16B chunks XOR-swizzled by s(r) =
// (r>>1)&3 (applied to the GLOBAL source chunk; LDS dests stay
// lane-contiguous as global_load_lds requires) -> 8-way bank alias -> 4-way.
// Symmetry handling identical to round 4.
__global__ __launch_bounds__(256, 2) void expsum_kernel(
    const __hip_bfloat16* __restrict__ h1, const __hip_bfloat16* __restrict__ h2,
    float* __restrict__ r1, float* __restrict__ r2,
    float* __restrict__ brow, float* __restrict__ bcol) {
  const int z = blockIdx.z;
  const int bi = blockIdx.x;
  const int bj = blockIdx.y;
  if (z != 2 && bi >= 2 * bj + 2) return;          // fully below diagonal
  const bool needPred = (z != 2) && (bi >= 2 * bj); // straddles diagonal
  const int i0 = bi * BM;
  const int j0 = bj * BN;

  __shared__ __align__(16) __hip_bfloat16 As[2][BM * 32];
  __shared__ __align__(16) __hip_bfloat16 Bs[2][BN * 32];
  __shared__ float lds_row[BM];
  __shared__ float lds_col[BN];

  const __hip_bfloat16* Ag = (z == 1) ? h2 : h1;
  const __hip_bfloat16* Bg = (z == 0) ? h1 : h2;

  const int t = threadIdx.x;
  const int wave = t >> 6;
  const int lane = t & 63;
  const int wm = wave >> 1;    // 0..1: 64-row half
  const int wn = wave & 1;     // 0..1: 128-col half
  const int l16 = lane & 15;
  const int kq = lane >> 4;    // 0..3

  // staging addresses: thread t covers physical 16B chunk (t&3) of row t>>2
  // (+64 per round); it must fetch LOGICAL chunk (t&3)^s(row); s(row) =
  // ((t>>2)>>1)&3 = (t>>3)&3 (round offsets are multiples of 64 -> s const).
  const int srow = t >> 2;
  const int swz = ((t & 3) ^ ((t >> 3) & 3)) * 8;  // element offset in row
  const size_t ab = (size_t)(i0 + srow) * DIM + swz;
  const size_t bb = (size_t)(j0 + srow) * DIM + swz;
  const int ldst = t * 16;

  // prologue: stage kb=0 into buffer 0
  {
    char* AsB = (char*)As[0];
    char* BsB = (char*)Bs[0];
    gload_lds16(Ag + ab, AsB + ldst);
    gload_lds16(Ag + ab + (size_t)64 * DIM, AsB + 4096 + ldst);
#pragma unroll
    for (int q = 0; q < 4; q++)
      gload_lds16(Bg + bb + (size_t)(q * 64) * DIM, BsB + q * 4096 + ldst);
  }

  f32x4 acc[4][8];
#pragma unroll
  for (int a = 0; a < 4; a++)
#pragma unroll
    for (int b = 0; b < 8; b++)
#pragma unroll
      for (int r = 0; r < 4; r++) acc[a][b][r] = 0.0f;

  // frag-read physical chunk: logical kq lives at kq ^ s(row); s(row) =
  // ((f*16+l16)>>1)&3 = (l16>>1)&3 (f*16 is a multiple of 32 in row units /
  // contributes 0 mod 4 after >>1). Byte offset within row:
  const int pfrag = (kq ^ ((l16 >> 1) & 3)) * 16;

  for (int kb = 0; kb < DIM / 32; kb++) {
    __syncthreads();  // drains stage(kb) (issued one full compute phase ago)
    if (kb + 1 < DIM / 32) {
      const int k0 = (kb + 1) * 32;
      char* AsB = (char*)As[(kb + 1) & 1];
      char* BsB = (char*)Bs[(kb + 1) & 1];
      gload_lds16(Ag + ab + k0, AsB + ldst);
      gload_lds16(Ag + ab + (size_t)64 * DIM + k0, AsB + 4096 + ldst);
#pragma unroll
      for (int q = 0; q < 4; q++)
        gload_lds16(Bg + bb + (size_t)(q * 64) * DIM + k0, BsB + q * 4096 + ldst);
    }
    const char* AsB = (const char*)As[kb & 1];
    const char* BsB = (const char*)Bs[kb & 1];

    bf16x8 afrag[4], bfrag[8];
#pragma unroll
    for (int f = 0; f < 4; f++)
      afrag[f] = *(const bf16x8*)(AsB + (wm * 64 + f * 16 + l16) * 64 + pfrag);
#pragma unroll
    for (int f = 0; f < 8; f++)
      bfrag[f] = *(const bf16x8*)(BsB + (wn * 128 + f * 16 + l16) * 64 + pfrag);
#pragma unroll
    for (int fm = 0; fm < 4; fm++)
#pragma unroll
      for (int fn = 0; fn < 8; fn++)
        acc[fm][fn] = __builtin_amdgcn_mfma_f32_16x16x32_bf16(
            afrag[fm], bfrag[fn], acc[fm][fn], 0, 0, 0);
  }

  // Epilogue. C/D layout: col = lane&15, row = kq*4 + reg.
  float rowp[4][4];
  float colp[8];
#pragma unroll
  for (int fm = 0; fm < 4; fm++)
#pragma unroll
    for (int r = 0; r < 4; r++) rowp[fm][r] = 0.0f;
#pragma unroll
  for (int fn = 0; fn < 8; fn++) colp[fn] = 0.0f;

  if (!needPred) {
#pragma unroll
    for (int fm = 0; fm < 4; fm++)
#pragma unroll
      for (int fn = 0; fn < 8; fn++)
#pragma unroll
        for (int r = 0; r < 4; r++) {
          const float e = __expf(acc[fm][fn][r] * INV_TAU);
          rowp[fm][r] += e;
          colp[fn] += e;
        }
  } else {
    const int gi_b = i0 + wm * 64 + kq * 4;   // + fm*16 + r
    const int gj_b = j0 + wn * 128 + l16;     // + fn*16
#pragma unroll
    for (int fm = 0; fm < 4; fm++)
#pragma unroll
      for (int fn = 0; fn < 8; fn++)
#pragma unroll
        for (int r = 0; r < 4; r++) {
          const int gi = gi_b + fm * 16 + r;
          const int gj = gj_b + fn * 16;
          const float e = __expf(acc[fm][fn][r] * INV_TAU);
          rowp[fm][r] += (gi <= gj) ? e : 0.0f;
          colp[fn] += (gi < gj) ? e : 0.0f;
        }
  }

  __syncthreads();  // last iter's ds_reads done before reusing nothing; order lds_row init
  if (t < BM) lds_row[t] = 0.0f;
  lds_col[t] = 0.0f;
  __syncthreads();

  // Row sums: reduce across the 16 lanes (cols) sharing kq.
#pragma unroll
  for (int fm = 0; fm < 4; fm++) {
#pragma unroll
    for (int r = 0; r < 4; r++) {
      float v = rowp[fm][r];
      v += __shfl_xor(v, 1);
      v += __shfl_xor(v, 2);
      v += __shfl_xor(v, 4);
      v += __shfl_xor(v, 8);
      if (l16 == 0) atomicAdd(&lds_row[wm * 64 + fm * 16 + kq * 4 + r], v);
    }
  }
  // Col sums: reduce across the 4 kq groups (rows).
#pragma unroll
  for (int fn = 0; fn < 8; fn++) {
    float v = colp[fn];
    v += __shfl_xor(v, 16);
    v += __shfl_xor(v, 32);
    if (kq == 0) atomicAdd(&lds_col[wn * 128 + fn * 16 + l16], v);
  }
  __syncthreads();

  if (z == 2) {
    if (t < BM) atomicAdd(&brow[i0 + t], lds_row[t]);
    atomicAdd(&bcol[j0 + t], lds_col[t]);
  } else {
    float* r = (z == 0) ? r1 : r2;
    if (t < BM) atomicAdd(&r[i0 + t], lds_row[t]);
    atomicAdd(&r[j0 + t], lds_col[t]);
  }
}

__global__ __launch_bounds__(256) void finalize_kernel(
    const float* __restrict__ r1, const float* __restrict__ r2,
    const float* __restrict__ brow, const float* __restrict__ bcol,
    const float* __restrict__ dvec, float* __restrict__ out) {
  const int i = blockIdx.x * 256 + threadIdx.x;
  const float den1 = r1[i] + brow[i] - EXP5;
  const float den2 = r2[i] + bcol[i] - EXP5;
  float v = 0.5f * (logf(den1) + logf(den2)) - INV_TAU * dvec[i];
  for (int m = 32; m; m >>= 1) v += __shfl_xor(v, m);
  __shared__ float red[4];
  const int wave = threadIdx.x >> 6;
  if ((threadIdx.x & 63) == 0) red[wave] = v;
  __syncthreads();
  if (threadIdx.x == 0) atomicAdd(out, red[0] + red[1] + red[2] + red[3]);
}

extern "C" void kernel_launch(void* const* d_in, const int* in_sizes, int n_in,
                              void* d_out, int out_size, void* d_ws, size_t ws_size,
                              hipStream_t stream) {
  const float* z1 = (const float*)d_in[0];
  const float* z2 = (const float*)d_in[1];
  float* out = (float*)d_out;

  char* ws = (char*)d_ws;
  __hip_bfloat16* h1 = (__hip_bfloat16*)ws;                   // 8 MiB
  __hip_bfloat16* h2 = (__hip_bfloat16*)(ws + 8388608);       // 8 MiB
  float* r1   = (float*)(ws + 16777216);
  float* r2   = r1 + N_ROWS;
  float* brow = r2 + N_ROWS;
  float* bcol = brow + N_ROWS;
  float* dvec = bcol + N_ROWS;

  normalize_kernel<<<N_ROWS / 4, 256, 0, stream>>>(z1, z2, h1, h2, dvec,
                                                   r1, r2, brow, bcol, out);
  expsum_kernel<<<dim3(64, 32, 3), 256, 0, stream>>>(h1, h2, r1, r2, brow, bcol);
  finalize_kernel<<<N_ROWS / 256, 256, 0, stream>>>(r1, r2, brow, bcol, dvec, out);
}

// Round 6
// 254.872 us; speedup vs baseline: 1.1743x; 1.1743x over previous
//
#include <hip/hip_runtime.h>
#include <hip/hip_bf16.h>
#include <math.h>
#include <stdint.h>

#define N_ROWS 8192
#define DIM 512
#define INV_TAU 5.0f
#define EXP5 148.41315910257660342f   // exp(1/tau) = exp(5)

typedef float f32x4 __attribute__((ext_vector_type(4)));
typedef long long i64;

__device__ __forceinline__ void gload_lds16(const void* g, void* l) {
  __builtin_amdgcn_global_load_lds(
      (__attribute__((address_space(1))) void*)(void*)g,
      (__attribute__((address_space(3))) void*)l,
      16, 0, 0);
}

// Block = 16 rows (one 16-row MFMA "group"). Thread t: row t>>4, k-span
// (t&15)*32..+31. Computes norms (16-lane butterfly), fp32 diag dot, and
// writes h as fp8 e4m3 in BOTH layouts:
//   normal : h[row][k]                   (B staging source)
//   packed : hp[g=row/16][kb=k/32][lane] (A-frag direct-load source; lane
//            l&15 = row-in-group, l>>4 = k-quarter -> 512B per (g,kb))
// Also zeroes r1/r2/brow/bcol/out (replaces memsets).
__global__ __launch_bounds__(256) void normalize_kernel(
    const float* __restrict__ z1, const float* __restrict__ z2,
    uint8_t* __restrict__ h1, uint8_t* __restrict__ h2,
    uint8_t* __restrict__ h1p, uint8_t* __restrict__ h2p,
    float* __restrict__ dvec,
    float* __restrict__ r1, float* __restrict__ r2,
    float* __restrict__ brow, float* __restrict__ bcol,
    float* __restrict__ out) {
  const int t = threadIdx.x;
  const int lr = t >> 4;          // row in group 0..15
  const int kb = t & 15;          // this thread's 32-elem k-block
  const int row = blockIdx.x * 16 + lr;
  const float4* p1 = (const float4*)(z1 + (size_t)row * DIM + kb * 32);
  const float4* p2 = (const float4*)(z2 + (size_t)row * DIM + kb * 32);
  float4 a[8], b[8];
  float s1 = 0.f, s2 = 0.f, s3 = 0.f;
#pragma unroll
  for (int i = 0; i < 8; i++) {
    a[i] = p1[i]; b[i] = p2[i];
    s1 += a[i].x*a[i].x + a[i].y*a[i].y + a[i].z*a[i].z + a[i].w*a[i].w;
    s2 += b[i].x*b[i].x + b[i].y*b[i].y + b[i].z*b[i].z + b[i].w*b[i].w;
    s3 += a[i].x*b[i].x + a[i].y*b[i].y + a[i].z*b[i].z + a[i].w*b[i].w;
  }
  // reduce across the 16 lanes sharing a row (lanes are contiguous)
  for (int m = 1; m <= 8; m <<= 1) {
    s1 += __shfl_xor(s1, m);
    s2 += __shfl_xor(s2, m);
    s3 += __shfl_xor(s3, m);
  }
  const float inv1 = 1.0f / fmaxf(sqrtf(s1), 1e-12f);
  const float inv2 = 1.0f / fmaxf(sqrtf(s2), 1e-12f);
  int w1[8], w2[8];
#pragma unroll
  for (int i = 0; i < 8; i++) {
    int w = __builtin_amdgcn_cvt_pk_fp8_f32(a[i].x*inv1, a[i].y*inv1, 0, false);
    w1[i] = __builtin_amdgcn_cvt_pk_fp8_f32(a[i].z*inv1, a[i].w*inv1, w, true);
    w = __builtin_amdgcn_cvt_pk_fp8_f32(b[i].x*inv2, b[i].y*inv2, 0, false);
    w2[i] = __builtin_amdgcn_cvt_pk_fp8_f32(b[i].z*inv2, b[i].w*inv2, w, true);
  }
  // normal layout: 32 contiguous fp8
  int4* o1 = (int4*)(h1 + (size_t)row * DIM + kb * 32);
  int4* o2 = (int4*)(h2 + (size_t)row * DIM + kb * 32);
  o1[0] = make_int4(w1[0], w1[1], w1[2], w1[3]);
  o1[1] = make_int4(w1[4], w1[5], w1[6], w1[7]);
  o2[0] = make_int4(w2[0], w2[1], w2[2], w2[3]);
  o2[1] = make_int4(w2[4], w2[5], w2[6], w2[7]);
  // packed layout: lane l = kq*16 + lr holds k = kq*8..+7 of this kb
  union { i64 q; int d[2]; } u;
  const size_t pb = (size_t)blockIdx.x * 8192 + kb * 512 + lr * 8;
#pragma unroll
  for (int kq = 0; kq < 4; kq++) {
    u.d[0] = w1[kq*2]; u.d[1] = w1[kq*2+1];
    *(i64*)(h1p + pb + kq * 128) = u.q;
    u.d[0] = w2[kq*2]; u.d[1] = w2[kq*2+1];
    *(i64*)(h2p + pb + kq * 128) = u.q;
  }
  if (kb == 0) dvec[row] = s3 * inv1 * inv2;
  if (t < 16) {
    const int i = blockIdx.x * 16 + t;
    r1[i] = 0.f; r2[i] = 0.f; brow[i] = 0.f; bcol[i] = 0.f;
    if (i == 0) out[0] = 0.f;
  }
}

// One kernel over the upper triangle of W W^T, W=[h1;h2] (16384 rows), in
// 128x128 tiles: 1-D grid of 8256 blocks, u -> (bi<=bj). Quadrants route
// operands/outputs: (bi,bj<64): h1 h1^T -> r1; (bi<64<=bj): h1 h2^T ->
// brow/bcol; (bi,bj>=64): h2 h2^T -> r2. Only bi==bj blocks predicate.
//
// Structure (barrier-free K-loop): B-tile (128 rows x full K=512 fp8, 64KB)
// staged ONCE into swizzled LDS; A-frags loaded straight from the packed
// global layout (one coalesced dwordx2 per frag) with 1-iter register
// prefetch. No __syncthreads inside the K-loop.
__global__ __launch_bounds__(256) void expsum_kernel(
    const uint8_t* __restrict__ h1, const uint8_t* __restrict__ h2,
    const uint8_t* __restrict__ h1p, const uint8_t* __restrict__ h2p,
    float* __restrict__ r1, float* __restrict__ r2,
    float* __restrict__ brow, float* __restrict__ bcol) {
  __shared__ __align__(16) uint8_t Bs[128 * 512];   // exactly 64 KB

  const int u = blockIdx.x;
  int bj = (int)((sqrt(8.0 * (double)u + 1.0) - 1.0) * 0.5);
  if (bj * (bj + 1) / 2 > u) bj--;
  if ((bj + 1) * (bj + 2) / 2 <= u) bj++;
  const int bi = u - bj * (bj + 1) / 2;
  const bool diagb = (bi == bj);

  const uint8_t* Ap = (bi < 64) ? h1p : h2p;
  const uint8_t* Bn = (bj < 64) ? h1 : h2;
  float* rowsOut = (bi < 64) ? ((bj < 64) ? r1 : brow) : r2;
  float* colsOut = (bj < 64) ? r1 : ((bi < 64) ? bcol : r2);
  const int iOutBase = (bi & 63) * 128;
  const int jOutBase = (bj & 63) * 128;

  const int t = threadIdx.x;
  const int wave = t >> 6;
  const int lane = t & 63;
  const int wm = wave >> 1;     // 0..1: 64-row half
  const int wn = wave & 1;      // 0..1: 64-col half
  const int l16 = lane & 15;
  const int kq = lane >> 4;     // 0..3

  // ---- A-frag prefetch for kb=0 (issued before staging to overlap) ----
  const uint8_t* Abase =
      Ap + ((size_t)((bi & 63) * 8 + wm * 4)) * 8192 + (size_t)lane * 8;
  i64 Areg[2][4];
#pragma unroll
  for (int f = 0; f < 4; f++)
    Areg[0][f] = *(const i64*)(Abase + (size_t)f * 8192);

  // ---- B staging: 16 rounds x 4KB (8 rows each), swizzled ----
  // LDS layout: row r, logical 16B chunk c stored at chunk c ^ (r&7).
  // Thread t covers physical chunk (t&31) of row (t>>5)+8*rnd; it fetches
  // logical chunk (t&31)^(r&7); r&7 == (t>>5)&7 (rnd*8 = 0 mod 8).
  {
    const int r_ = t >> 5;
    const int clog = (t & 31) ^ (r_ & 7);
    const uint8_t* src = Bn + (size_t)(jOutBase + r_) * DIM + clog * 16;
    uint8_t* dst = Bs + t * 16;
#pragma unroll
    for (int rnd = 0; rnd < 16; rnd++)
      gload_lds16(src + (size_t)rnd * 8 * DIM, dst + rnd * 4096);
  }

  f32x4 acc[4][4];
#pragma unroll
  for (int a = 0; a < 4; a++)
#pragma unroll
    for (int b = 0; b < 4; b++)
#pragma unroll
      for (int r = 0; r < 4; r++) acc[a][b][r] = 0.0f;

  // B-frag LDS address components: row rB = wn*64 + f*16 + l16, byte
  // addr = rB*512 + ((2*kb + (kq>>1)) ^ (rB&7))*16 + (kq&1)*8
  int bbase[4], bxor[4];
#pragma unroll
  for (int f = 0; f < 4; f++) {
    const int rB = wn * 64 + f * 16 + l16;
    bbase[f] = rB * 512 + (kq & 1) * 8;
    bxor[f] = rB & 7;
  }
  const int ckq = kq >> 1;

  __syncthreads();   // the ONLY pre-epilogue barrier: B tile ready

#pragma unroll
  for (int kb = 0; kb < 16; kb++) {
    const int cur = kb & 1;
    if (kb < 15) {
#pragma unroll
      for (int f = 0; f < 4; f++)
        Areg[cur ^ 1][f] =
            *(const i64*)(Abase + (size_t)f * 8192 + (kb + 1) * 512);
    }
    i64 bf[4];
    const int ck = 2 * kb + ckq;
#pragma unroll
    for (int f = 0; f < 4; f++)
      bf[f] = *(const i64*)(Bs + bbase[f] + ((ck ^ bxor[f]) << 4));
#pragma unroll
    for (int fm = 0; fm < 4; fm++)
#pragma unroll
      for (int fn = 0; fn < 4; fn++)
        acc[fm][fn] = __builtin_amdgcn_mfma_f32_16x16x32_fp8_fp8(
            Areg[cur][fm], bf[fn], acc[fm][fn], 0, 0, 0);
  }

  // ---- Epilogue. C/D layout: col = lane&15, row = kq*4 + reg. ----
  float rowp[4][4];
  float colp[4];
#pragma unroll
  for (int fm = 0; fm < 4; fm++)
#pragma unroll
    for (int r = 0; r < 4; r++) rowp[fm][r] = 0.0f;
#pragma unroll
  for (int fn = 0; fn < 4; fn++) colp[fn] = 0.0f;

  if (!diagb) {
#pragma unroll
    for (int fm = 0; fm < 4; fm++)
#pragma unroll
      for (int fn = 0; fn < 4; fn++)
#pragma unroll
        for (int r = 0; r < 4; r++) {
          const float e = __expf(acc[fm][fn][r] * INV_TAU);
          rowp[fm][r] += e;
          colp[fn] += e;
        }
  } else {
    // within-tile indices (i0==j0): rows keep ti<=tj, cols keep ti<tj
#pragma unroll
    for (int fm = 0; fm < 4; fm++)
#pragma unroll
      for (int fn = 0; fn < 4; fn++)
#pragma unroll
        for (int r = 0; r < 4; r++) {
          const int ti = wm * 64 + fm * 16 + kq * 4 + r;
          const int tj = wn * 64 + fn * 16 + l16;
          const float e = __expf(acc[fm][fn][r] * INV_TAU);
          rowp[fm][r] += (ti <= tj) ? e : 0.0f;
          colp[fn] += (ti < tj) ? e : 0.0f;
        }
  }

  // lds_row/lds_col alias into Bs — safe only after ALL waves left the
  // K-loop, hence the barrier.
  __syncthreads();
  float* lds_row = (float*)Bs;
  float* lds_col = lds_row + 128;
  if (t < 128) lds_row[t] = 0.0f; else lds_col[t - 128] = 0.0f;
  __syncthreads();

#pragma unroll
  for (int fm = 0; fm < 4; fm++) {
#pragma unroll
    for (int r = 0; r < 4; r++) {
      float v = rowp[fm][r];
      v += __shfl_xor(v, 1);
      v += __shfl_xor(v, 2);
      v += __shfl_xor(v, 4);
      v += __shfl_xor(v, 8);
      if (l16 == 0) atomicAdd(&lds_row[wm * 64 + fm * 16 + kq * 4 + r], v);
    }
  }
#pragma unroll
  for (int fn = 0; fn < 4; fn++) {
    float v = colp[fn];
    v += __shfl_xor(v, 16);
    v += __shfl_xor(v, 32);
    if (kq == 0) atomicAdd(&lds_col[wn * 64 + fn * 16 + l16], v);
  }
  __syncthreads();

  if (t < 128) atomicAdd(&rowsOut[iOutBase + t], lds_row[t]);
  else         atomicAdd(&colsOut[jOutBase + (t - 128)], lds_col[t - 128]);
}

__global__ __launch_bounds__(256) void finalize_kernel(
    const float* __restrict__ r1, const float* __restrict__ r2,
    const float* __restrict__ brow, const float* __restrict__ bcol,
    const float* __restrict__ dvec, float* __restrict__ out) {
  const int i = blockIdx.x * 256 + threadIdx.x;
  const float den1 = r1[i] + brow[i] - EXP5;
  const float den2 = r2[i] + bcol[i] - EXP5;
  float v = 0.5f * (logf(den1) + logf(den2)) - INV_TAU * dvec[i];
  for (int m = 32; m; m >>= 1) v += __shfl_xor(v, m);
  __shared__ float red[4];
  const int wave = threadIdx.x >> 6;
  if ((threadIdx.x & 63) == 0) red[wave] = v;
  __syncthreads();
  if (threadIdx.x == 0) atomicAdd(out, red[0] + red[1] + red[2] + red[3]);
}

extern "C" void kernel_launch(void* const* d_in, const int* in_sizes, int n_in,
                              void* d_out, int out_size, void* d_ws, size_t ws_size,
                              hipStream_t stream) {
  const float* z1 = (const float*)d_in[0];
  const float* z2 = (const float*)d_in[1];
  float* out = (float*)d_out;

  char* ws = (char*)d_ws;
  uint8_t* h1  = (uint8_t*)ws;                 // 4 MiB fp8 normal
  uint8_t* h2  = (uint8_t*)(ws + (4u << 20));  // 4 MiB
  uint8_t* h1p = (uint8_t*)(ws + (8u << 20));  // 4 MiB fp8 packed
  uint8_t* h2p = (uint8_t*)(ws + (12u << 20)); // 4 MiB
  float* r1   = (float*)(ws + (16u << 20));
  float* r2   = r1 + N_ROWS;
  float* brow = r2 + N_ROWS;
  float* bcol = brow + N_ROWS;
  float* dvec = bcol + N_ROWS;

  normalize_kernel<<<N_ROWS / 16, 256, 0, stream>>>(
      z1, z2, h1, h2, h1p, h2p, dvec, r1, r2, brow, bcol, out);
  expsum_kernel<<<8256, 256, 0, stream>>>(h1, h2, h1p, h2p, r1, r2, brow, bcol);
  finalize_kernel<<<N_ROWS / 256, 256, 0, stream>>>(r1, r2, brow, bcol, dvec, out);
}

// Round 7
// 232.697 us; speedup vs baseline: 1.2862x; 1.0953x over previous
//
#include <hip/hip_runtime.h>
#include <hip/hip_bf16.h>
#include <math.h>
#include <stdint.h>

#define N_ROWS 8192
#define DIM 512
#define INV_TAU 5.0f
#define EXP5 148.41315910257660342f   // exp(1/tau) = exp(5)

typedef float f32x4 __attribute__((ext_vector_type(4)));
typedef long long i64;

// Block = 16 rows (one MFMA group). Thread t: row t>>4, k-span (t&15)*32..+31.
// Norms via 16-lane butterfly, fp32 diag dot, fp8 e4m3 quantization into the
// MFMA-fragment-packed layout ONLY:
//   hp[g=row/16][kb=k/32][lane]  (lane l: row l&15, k-quarter l>>4; 512B per
//   (g,kb) -> one coalesced dwordx2 per A- OR B-frag in expsum).
// Packed scatter goes through LDS so the global writes are coalesced int4.
// Also zeroes r1/r2/brow/bcol/out.
__global__ __launch_bounds__(256) void normalize_kernel(
    const float* __restrict__ z1, const float* __restrict__ z2,
    uint8_t* __restrict__ h1p, uint8_t* __restrict__ h2p,
    float* __restrict__ dvec,
    float* __restrict__ r1, float* __restrict__ r2,
    float* __restrict__ brow, float* __restrict__ bcol,
    float* __restrict__ out) {
  __shared__ __align__(16) uint8_t L[16384];  // 8KB h1-part, 8KB h2-part
  const int t = threadIdx.x;
  const int lr = t >> 4;          // row in group 0..15
  const int kb = t & 15;          // this thread's 32-elem k-block
  const int row = blockIdx.x * 16 + lr;
  const float4* p1 = (const float4*)(z1 + (size_t)row * DIM + kb * 32);
  const float4* p2 = (const float4*)(z2 + (size_t)row * DIM + kb * 32);
  float4 a[8], b[8];
  float s1 = 0.f, s2 = 0.f, s3 = 0.f;
#pragma unroll
  for (int i = 0; i < 8; i++) {
    a[i] = p1[i]; b[i] = p2[i];
    s1 += a[i].x*a[i].x + a[i].y*a[i].y + a[i].z*a[i].z + a[i].w*a[i].w;
    s2 += b[i].x*b[i].x + b[i].y*b[i].y + b[i].z*b[i].z + b[i].w*b[i].w;
    s3 += a[i].x*b[i].x + a[i].y*b[i].y + a[i].z*b[i].z + a[i].w*b[i].w;
  }
  // reduce across the 16 contiguous lanes sharing a row
  for (int m = 1; m <= 8; m <<= 1) {
    s1 += __shfl_xor(s1, m);
    s2 += __shfl_xor(s2, m);
    s3 += __shfl_xor(s3, m);
  }
  const float inv1 = 1.0f / fmaxf(sqrtf(s1), 1e-12f);
  const float inv2 = 1.0f / fmaxf(sqrtf(s2), 1e-12f);
  int w1[8], w2[8];
#pragma unroll
  for (int i = 0; i < 8; i++) {
    int w = __builtin_amdgcn_cvt_pk_fp8_f32(a[i].x*inv1, a[i].y*inv1, 0, false);
    w1[i] = __builtin_amdgcn_cvt_pk_fp8_f32(a[i].z*inv1, a[i].w*inv1, w, true);
    w = __builtin_amdgcn_cvt_pk_fp8_f32(b[i].x*inv2, b[i].y*inv2, 0, false);
    w2[i] = __builtin_amdgcn_cvt_pk_fp8_f32(b[i].z*inv2, b[i].w*inv2, w, true);
  }
  // scatter into LDS in packed order: byte = kb*512 + q*128 + lr*8
  union { i64 q; int d[2]; } u;
  const int lbase = kb * 512 + lr * 8;
#pragma unroll
  for (int q = 0; q < 4; q++) {
    u.d[0] = w1[q*2]; u.d[1] = w1[q*2+1];
    *(i64*)(L + lbase + q * 128) = u.q;
    u.d[0] = w2[q*2]; u.d[1] = w2[q*2+1];
    *(i64*)(L + 8192 + lbase + q * 128) = u.q;
  }
  if (kb == 0) dvec[row] = s3 * inv1 * inv2;
  if (t < 16) {
    const int i = blockIdx.x * 16 + t;
    r1[i] = 0.f; r2[i] = 0.f; brow[i] = 0.f; bcol[i] = 0.f;
    if (i == 0) out[0] = 0.f;
  }
  __syncthreads();
  // coalesced write-out: one group's packed data is 8KB contiguous
  const size_t gb = (size_t)blockIdx.x * 8192;
  int4* g1 = (int4*)(h1p + gb);
  int4* g2 = (int4*)(h2p + gb);
  const int4* Lv = (const int4*)L;
  g1[t]       = Lv[t];
  g1[t + 256] = Lv[t + 256];
  g2[t]       = Lv[t + 512];
  g2[t + 256] = Lv[t + 768];
}

// Upper triangle of W W^T, W=[h1;h2] (16384 rows), 128x128 tiles, 8256
// blocks. Quadrants route outputs (verified r6). NO LDS operands: both A and
// B frags are single coalesced dwordx2 loads from the packed layout
// (L2/L3-resident, 8MB total), register double-buffered; the K-loop has no
// barriers and no ds_reads. blockIdx striped by &7 so each XCD works a
// contiguous triangle stripe (per-XCD L2 locality).
__global__ __launch_bounds__(256) void expsum_kernel(
    const uint8_t* __restrict__ h1p, const uint8_t* __restrict__ h2p,
    float* __restrict__ r1, float* __restrict__ r2,
    float* __restrict__ brow, float* __restrict__ bcol) {
  __shared__ float lds_red[256];

  const int u = (blockIdx.x & 7) * 1032 + (blockIdx.x >> 3);  // 8256 = 8*1032
  int bj = (int)((sqrt(8.0 * (double)u + 1.0) - 1.0) * 0.5);
  if (bj * (bj + 1) / 2 > u) bj--;
  if ((bj + 1) * (bj + 2) / 2 <= u) bj++;
  const int bi = u - bj * (bj + 1) / 2;
  const bool diagb = (bi == bj);

  const uint8_t* Ap = (bi < 64) ? h1p : h2p;
  const uint8_t* Bp = (bj < 64) ? h1p : h2p;
  float* rowsOut = (bi < 64) ? ((bj < 64) ? r1 : brow) : r2;
  float* colsOut = (bj < 64) ? r1 : ((bi < 64) ? bcol : r2);
  const int iOutBase = (bi & 63) * 128;
  const int jOutBase = (bj & 63) * 128;

  const int t = threadIdx.x;
  const int wave = t >> 6;
  const int lane = t & 63;
  const int wm = wave >> 1;     // 0..1: 64-row half
  const int wn = wave & 1;      // 0..1: 64-col half
  const int l16 = lane & 15;
  const int kq = lane >> 4;     // 0..3

  // frag streams: group g holds 16 rows; frag f of this wave = group base+f.
  const uint8_t* Abase =
      Ap + ((size_t)((bi & 63) * 8 + wm * 4)) * 8192 + (size_t)lane * 8;
  const uint8_t* Bbase =
      Bp + ((size_t)((bj & 63) * 8 + wn * 4)) * 8192 + (size_t)lane * 8;

  i64 Ar[2][4], Br[2][4];
#pragma unroll
  for (int f = 0; f < 4; f++) {
    Ar[0][f] = *(const i64*)(Abase + (size_t)f * 8192);
    Br[0][f] = *(const i64*)(Bbase + (size_t)f * 8192);
  }

  f32x4 acc[4][4];
#pragma unroll
  for (int a = 0; a < 4; a++)
#pragma unroll
    for (int b = 0; b < 4; b++)
#pragma unroll
      for (int r = 0; r < 4; r++) acc[a][b][r] = 0.0f;

#pragma unroll
  for (int kb = 0; kb < 16; kb++) {
    const int cur = kb & 1;
    if (kb < 15) {
#pragma unroll
      for (int f = 0; f < 4; f++) {
        Ar[cur ^ 1][f] = *(const i64*)(Abase + (size_t)f * 8192 + (kb + 1) * 512);
        Br[cur ^ 1][f] = *(const i64*)(Bbase + (size_t)f * 8192 + (kb + 1) * 512);
      }
    }
#pragma unroll
    for (int fm = 0; fm < 4; fm++)
#pragma unroll
      for (int fn = 0; fn < 4; fn++)
        acc[fm][fn] = __builtin_amdgcn_mfma_f32_16x16x32_fp8_fp8(
            Ar[cur][fm], Br[cur][fn], acc[fm][fn], 0, 0, 0);
  }

  // ---- Epilogue (r6-verified). C/D layout: col = lane&15, row = kq*4+reg ----
  float rowp[4][4];
  float colp[4];
#pragma unroll
  for (int fm = 0; fm < 4; fm++)
#pragma unroll
    for (int r = 0; r < 4; r++) rowp[fm][r] = 0.0f;
#pragma unroll
  for (int fn = 0; fn < 4; fn++) colp[fn] = 0.0f;

  if (!diagb) {
#pragma unroll
    for (int fm = 0; fm < 4; fm++)
#pragma unroll
      for (int fn = 0; fn < 4; fn++)
#pragma unroll
        for (int r = 0; r < 4; r++) {
          const float e = __expf(acc[fm][fn][r] * INV_TAU);
          rowp[fm][r] += e;
          colp[fn] += e;
        }
  } else {
    // within-tile indices (i0==j0): rows keep ti<=tj, cols keep ti<tj
#pragma unroll
    for (int fm = 0; fm < 4; fm++)
#pragma unroll
      for (int fn = 0; fn < 4; fn++)
#pragma unroll
        for (int r = 0; r < 4; r++) {
          const int ti = wm * 64 + fm * 16 + kq * 4 + r;
          const int tj = wn * 64 + fn * 16 + l16;
          const float e = __expf(acc[fm][fn][r] * INV_TAU);
          rowp[fm][r] += (ti <= tj) ? e : 0.0f;
          colp[fn] += (ti < tj) ? e : 0.0f;
        }
  }

  float* lds_row = lds_red;
  float* lds_col = lds_red + 128;
  if (t < 128) lds_row[t] = 0.0f; else lds_col[t - 128] = 0.0f;
  __syncthreads();

#pragma unroll
  for (int fm = 0; fm < 4; fm++) {
#pragma unroll
    for (int r = 0; r < 4; r++) {
      float v = rowp[fm][r];
      v += __shfl_xor(v, 1);
      v += __shfl_xor(v, 2);
      v += __shfl_xor(v, 4);
      v += __shfl_xor(v, 8);
      if (l16 == 0) atomicAdd(&lds_row[wm * 64 + fm * 16 + kq * 4 + r], v);
    }
  }
#pragma unroll
  for (int fn = 0; fn < 4; fn++) {
    float v = colp[fn];
    v += __shfl_xor(v, 16);
    v += __shfl_xor(v, 32);
    if (kq == 0) atomicAdd(&lds_col[wn * 64 + fn * 16 + l16], v);
  }
  __syncthreads();

  if (t < 128) atomicAdd(&rowsOut[iOutBase + t], lds_row[t]);
  else         atomicAdd(&colsOut[jOutBase + (t - 128)], lds_col[t - 128]);
}

__global__ __launch_bounds__(256) void finalize_kernel(
    const float* __restrict__ r1, const float* __restrict__ r2,
    const float* __restrict__ brow, const float* __restrict__ bcol,
    const float* __restrict__ dvec, float* __restrict__ out) {
  const int i = blockIdx.x * 256 + threadIdx.x;
  const float den1 = r1[i] + brow[i] - EXP5;
  const float den2 = r2[i] + bcol[i] - EXP5;
  float v = 0.5f * (logf(den1) + logf(den2)) - INV_TAU * dvec[i];
  for (int m = 32; m; m >>= 1) v += __shfl_xor(v, m);
  __shared__ float red[4];
  const int wave = threadIdx.x >> 6;
  if ((threadIdx.x & 63) == 0) red[wave] = v;
  __syncthreads();
  if (threadIdx.x == 0) atomicAdd(out, red[0] + red[1] + red[2] + red[3]);
}

extern "C" void kernel_launch(void* const* d_in, const int* in_sizes, int n_in,
                              void* d_out, int out_size, void* d_ws, size_t ws_size,
                              hipStream_t stream) {
  const float* z1 = (const float*)d_in[0];
  const float* z2 = (const float*)d_in[1];
  float* out = (float*)d_out;

  char* ws = (char*)d_ws;
  uint8_t* h1p = (uint8_t*)ws;                 // 4 MiB fp8 packed
  uint8_t* h2p = (uint8_t*)(ws + (4u << 20));  // 4 MiB
  float* r1   = (float*)(ws + (8u << 20));
  float* r2   = r1 + N_ROWS;
  float* brow = r2 + N_ROWS;
  float* bcol = brow + N_ROWS;
  float* dvec = bcol + N_ROWS;

  normalize_kernel<<<N_ROWS / 16, 256, 0, stream>>>(
      z1, z2, h1p, h2p, dvec, r1, r2, brow, bcol, out);
  expsum_kernel<<<8256, 256, 0, stream>>>(h1p, h2p, r1, r2, brow, bcol);
  finalize_kernel<<<N_ROWS / 256, 256, 0, stream>>>(r1, r2, brow, bcol, dvec, out);
}